// Round 8
// baseline (121.123 us; speedup 1.0000x reference)
//
#include <hip/hip_runtime.h>

// out[b,i,j] = conv3x3_valid(inp, c*k)[b,i,j]
// c = vt(I=1) from the LIF scan (linear in I; spike/clamp provably inactive
// since I < 9 < 14 for all 1000 steps). c folded into the taps.
//
// R8: wave-autonomous pipeline, ZERO barriers. R5/R6/R7 (block-barrier
// structures) all plateau ~30us; the shared ingredient is s_barrier convoy.
// A 3x3 stencil needs no cross-wave sharing: each wave owns an 8-output-row
// slab and a private 5-slot x 2KB LDS row ring. global_load_lds is per-wave
// (wave-uniform base), so the only sync is the wave's own s_waitcnt vmcnt(N).
// Body t: issue DMA for input row t+4, vmcnt-wait just enough to drain row
// t+2's pair (2 newer pairs + stores stay in flight), ds_read row t+2,
// store output row t. vmcnt constants use the provable MINIMUM of 2 store
// instructions per body -> correct even if the compiler emits 2 instead of 3.
// Rolling h-sums carry across rows (each input row ds_read once per wave).
// LDS 4 waves x 5 x 2048B = 40960 B -> 4 blocks/CU; 1024 blocks co-resident.

#define RING 5

__device__ static inline void async_copy16(const float* gsrc, float* ldst) {
    __builtin_amdgcn_global_load_lds(
        (const __attribute__((address_space(1))) void*)gsrc,
        (__attribute__((address_space(3))) void*)ldst, 16, 0, 0);
}

__global__ __launch_bounds__(256) void snn_conv_wave_kernel(
    const float* __restrict__ inp, const float* __restrict__ kw,
    float* __restrict__ out, float c)
{
    __shared__ float tile[4 * RING * 512];       // 40960 B

    const int tid  = threadIdx.x;
    const int lane = tid & 63;
    const int wv   = tid >> 6;
    const int b    = blockIdx.y;
    const int ib0  = (blockIdx.x * 4 + wv) * 8;  // wave's first output row (0..504)

    float* wtile = tile + wv * (RING * 512);     // private per-wave ring
    const float* gbase = inp + (size_t)b * 262144;   // 512*512

    // taps first (uniform addr -> s_load/lgkmcnt; even if vectorized they are
    // OLDER than all DMA pairs, so vmcnt constants below stay correct)
    const float k00 = kw[0]*c, k01 = kw[1]*c, k02 = kw[2]*c;
    const float k10 = kw[3]*c, k11 = kw[4]*c, k12 = kw[5]*c;
    const float k20 = kw[6]*c, k21 = kw[7]*c, k22 = kw[8]*c;

    // DMA input row ib0+g into ring slot g%RING: 2 wave-instrs (2048 B)
#define STAGE(g)                                                          \
    {   const float* _gp = gbase + (size_t)min(ib0 + (g), 511) * 512;     \
        float* _l = wtile + ((g) % RING) * 512;                           \
        async_copy16(_gp + lane * 4,       _l + lane * 4);                \
        async_copy16(_gp + 256 + lane * 4, _l + 256 + lane * 4); }

    STAGE(0) STAGE(1) STAGE(2) STAGE(3)          // 8 vm ops in flight

    const int  jj = lane << 3;                   // cols jj..jj+7
    const bool ml = (lane < 63);

    float x0,x1,x2,x3,x4,x5,x6,x7,x8,x9;
#define LOADX(g)                                                          \
    {   const float* _p = wtile + ((g) % RING) * 512 + jj;                \
        float4 _a = *(const float4*)_p;                                   \
        float4 _b = *(const float4*)(_p + 4);                             \
        float2 _c = *(const float2*)(ml ? _p + 8 : _p);                   \
        x0=_a.x; x1=_a.y; x2=_a.z; x3=_a.w;                               \
        x4=_b.x; x5=_b.y; x6=_b.z; x7=_b.w; x8=_c.x; x9=_c.y; }

    // warm-up: drain pairs for rows 0,1 (leave rows 2,3 flying)
    asm volatile("s_waitcnt vmcnt(4)" ::: "memory");

    float a2[8], a1[8], o[8];
    LOADX(0);
    a2[0]=k00*x0+k01*x1+k02*x2; a2[1]=k00*x1+k01*x2+k02*x3;
    a2[2]=k00*x2+k01*x3+k02*x4; a2[3]=k00*x3+k01*x4+k02*x5;
    a2[4]=k00*x4+k01*x5+k02*x6; a2[5]=k00*x5+k01*x6+k02*x7;
    a2[6]=k00*x6+k01*x7+k02*x8; a2[7]=k00*x7+k01*x8+k02*x9;
    LOADX(1);
    a1[0]=k00*x0+k01*x1+k02*x2; a2[0]+=k10*x0+k11*x1+k12*x2;
    a1[1]=k00*x1+k01*x2+k02*x3; a2[1]+=k10*x1+k11*x2+k12*x3;
    a1[2]=k00*x2+k01*x3+k02*x4; a2[2]+=k10*x2+k11*x3+k12*x4;
    a1[3]=k00*x3+k01*x4+k02*x5; a2[3]+=k10*x3+k11*x4+k12*x5;
    a1[4]=k00*x4+k01*x5+k02*x6; a2[4]+=k10*x4+k11*x5+k12*x6;
    a1[5]=k00*x5+k01*x6+k02*x7; a2[5]+=k10*x5+k11*x6+k12*x7;
    a1[6]=k00*x6+k01*x7+k02*x8; a2[6]+=k10*x6+k11*x7+k12*x8;
    a1[7]=k00*x7+k01*x8+k02*x9; a2[7]+=k10*x7+k11*x8+k12*x9;

    float* obase = out + (size_t)b * 260100;     // 510*510

    // per-body vmcnt: drains row(t+2)'s pair assuming >=2 stores/body
    // t:      0  1  2  3  4  5  6  7
    // vmcnt:  4  6  8  8  8  8  6  4
#define BODY(t, N)                                                        \
    {   if ((t) + 4 <= 9) STAGE((t) + 4)                                  \
        asm volatile("s_waitcnt vmcnt(" #N ")" ::: "memory");             \
        LOADX((t) + 2);                                                   \
        o[0]=a2[0]+k20*x0+k21*x1+k22*x2; o[1]=a2[1]+k20*x1+k21*x2+k22*x3; \
        o[2]=a2[2]+k20*x2+k21*x3+k22*x4; o[3]=a2[3]+k20*x3+k21*x4+k22*x5; \
        o[4]=a2[4]+k20*x4+k21*x5+k22*x6; o[5]=a2[5]+k20*x5+k21*x6+k22*x7; \
        o[6]=a2[6]+k20*x6+k21*x7+k22*x8; o[7]=a2[7]+k20*x7+k21*x8+k22*x9; \
        const int orow = ib0 + (t);                                       \
        if (orow < 510) {                                                 \
            float* q = obase + (size_t)orow * 510 + jj;                   \
            if ((orow & 1) == 0) {      /* byte offset % 16 == 0 */       \
                *(float4*)q = make_float4(o[0],o[1],o[2],o[3]);           \
                if (ml) *(float4*)(q+4) = make_float4(o[4],o[5],o[6],o[7]);\
                else    *(float2*)(q+4) = make_float2(o[4],o[5]);         \
            } else {                    /* byte offset % 16 == 8 */       \
                *(float2*)q     = make_float2(o[0],o[1]);                 \
                *(float4*)(q+2) = make_float4(o[2],o[3],o[4],o[5]);       \
                if (ml) *(float2*)(q+6) = make_float2(o[6],o[7]);         \
            }                                                             \
        }                                                                 \
        a2[0]=a1[0]+k10*x0+k11*x1+k12*x2; a2[1]=a1[1]+k10*x1+k11*x2+k12*x3;\
        a2[2]=a1[2]+k10*x2+k11*x3+k12*x4; a2[3]=a1[3]+k10*x3+k11*x4+k12*x5;\
        a2[4]=a1[4]+k10*x4+k11*x5+k12*x6; a2[5]=a1[5]+k10*x5+k11*x6+k12*x7;\
        a2[6]=a1[6]+k10*x6+k11*x7+k12*x8; a2[7]=a1[7]+k10*x7+k11*x8+k12*x9;\
        a1[0]=k00*x0+k01*x1+k02*x2; a1[1]=k00*x1+k01*x2+k02*x3;           \
        a1[2]=k00*x2+k01*x3+k02*x4; a1[3]=k00*x3+k01*x4+k02*x5;           \
        a1[4]=k00*x4+k01*x5+k02*x6; a1[5]=k00*x5+k01*x6+k02*x7;           \
        a1[6]=k00*x6+k01*x7+k02*x8; a1[7]=k00*x7+k01*x8+k02*x9; }

    BODY(0, 4) BODY(1, 6) BODY(2, 8) BODY(3, 8)
    BODY(4, 8) BODY(5, 8) BODY(6, 6) BODY(7, 4)

#undef BODY
#undef LOADX
#undef STAGE
}

extern "C" void kernel_launch(void* const* d_in, const int* in_sizes, int n_in,
                              void* d_out, int out_size, void* d_ws, size_t ws_size,
                              hipStream_t stream) {
    (void)in_sizes; (void)n_in; (void)d_ws; (void)ws_size; (void)out_size;
    const float* inp = (const float*)d_in[0];
    const float* kw  = (const float*)d_in[1];
    float* out = (float*)d_out;

    // Closed-form LIF scan with I = 1 (double precision; exact by linearity).
    double v = 0.0;
    v = v + (3000.0 * 1.0 - v) / 30000.0 * 0.01;   // = 0.001
    double vt = v;
    for (int i = 0; i < 999; ++i) {
        v  = v + (3000.0 - v) / 30000.0 * 0.01;
        vt = (v + vt) / 1000.0;
    }
    float c = (float)vt;   // ~0.99983...

    dim3 block(256, 1, 1);
    dim3 grid(16, 64, 1);  // 64 wave-slabs/batch x 64 batches = 4096 waves
    hipLaunchKernelGGL(snn_conv_wave_kernel, grid, block, 0, stream,
                       inp, kw, out, c);
}